// Round 1
// baseline (811.608 us; speedup 1.0000x reference)
//
#include <hip/hip_runtime.h>
#include <math.h>

#define N_NODES 50000
#define N_EDGES 800000
#define E_TOT   850000   // edges + self loops
#define F_IN    256
#define F1      512      // HEADS*HID
#define HID     128
#define HEADS   4
#define F_OUT   64

__device__ __forceinline__ float lrelu(float x){ return x > 0.f ? x : 0.2f*x; }
__device__ __forceinline__ float elu(float x){ return x > 0.f ? x : expm1f(x); }

// ---------------- CSR build ----------------
__global__ void hist_kernel(const int* __restrict__ ei, int* __restrict__ deg){
  int e = blockIdx.x*blockDim.x + threadIdx.x;
  if (e >= E_TOT) return;
  int dst = (e < N_EDGES) ? ei[N_EDGES + e] : (e - N_EDGES);
  atomicAdd(&deg[dst], 1);
}

__global__ __launch_bounds__(1024) void scan_kernel(const int* __restrict__ deg,
                                                    int* __restrict__ offs){
  __shared__ int sdata[1024];
  __shared__ int sbase;
  int tid = threadIdx.x;
  if (tid == 0) sbase = 0;
  __syncthreads();
  for (int c = 0; c*1024 < N_NODES; ++c){
    int i = c*1024 + tid;
    int v = (i < N_NODES) ? deg[i] : 0;
    sdata[tid] = v; __syncthreads();
    #pragma unroll
    for (int off = 1; off < 1024; off <<= 1){
      int t = (tid >= off) ? sdata[tid - off] : 0;
      __syncthreads();
      sdata[tid] += t;
      __syncthreads();
    }
    if (i < N_NODES) offs[i] = sbase + sdata[tid] - v;   // exclusive
    __syncthreads();
    if (tid == 1023) sbase += sdata[1023];
    __syncthreads();
  }
  if (tid == 0) offs[N_NODES] = sbase;   // == E_TOT
}

__global__ void scatter_kernel(const int* __restrict__ ei, const int* __restrict__ offs,
                               int* __restrict__ cur, int* __restrict__ ssrc){
  int e = blockIdx.x*blockDim.x + threadIdx.x;
  if (e >= E_TOT) return;
  int src, dst;
  if (e < N_EDGES){ src = ei[e]; dst = ei[N_EDGES + e]; }
  else            { src = e - N_EDGES; dst = src; }
  int pos = offs[dst] + atomicAdd(&cur[dst], 1);
  ssrc[pos] = src;
}

// ---------------- GEMM: C[M,N] = A[M,K] @ B[K,N], 64x64 tile ----------------
template<int K>
__global__ __launch_bounds__(256) void gemm64(const float* __restrict__ A,
                                              const float* __restrict__ B,
                                              float* __restrict__ C,
                                              int M, int N){
  __shared__ float As[16][64];
  __shared__ float Bs[16][64];
  const int tid = threadIdx.x;
  const int tx = tid & 15, ty = tid >> 4;
  const int m0 = blockIdx.x * 64;
  const int n0 = blockIdx.y * 64;
  const int arow = tid >> 2;          // 0..63
  const int akk  = (tid & 3) * 4;     // 0,4,8,12
  const int brow = tid >> 4;          // 0..15
  const int bcol = (tid & 15) * 4;    // 0..60
  float acc[4][4] = {};
  for (int k0 = 0; k0 < K; k0 += 16){
    float4 a4 = {0.f,0.f,0.f,0.f};
    if (m0 + arow < M)
      a4 = *(const float4*)(A + (size_t)(m0 + arow)*K + k0 + akk);
    As[akk+0][arow] = a4.x; As[akk+1][arow] = a4.y;
    As[akk+2][arow] = a4.z; As[akk+3][arow] = a4.w;
    *(float4*)&Bs[brow][bcol] =
      *(const float4*)(B + (size_t)(k0 + brow)*N + n0 + bcol);
    __syncthreads();
    #pragma unroll
    for (int k = 0; k < 16; ++k){
      const float4 av = *(const float4*)&As[k][ty*4];
      const float4 bv = *(const float4*)&Bs[k][tx*4];
      const float a[4] = {av.x, av.y, av.z, av.w};
      const float b[4] = {bv.x, bv.y, bv.z, bv.w};
      #pragma unroll
      for (int i = 0; i < 4; ++i)
        #pragma unroll
        for (int j = 0; j < 4; ++j)
          acc[i][j] = fmaf(a[i], b[j], acc[i][j]);
    }
    __syncthreads();
  }
  #pragma unroll
  for (int i = 0; i < 4; ++i){
    int row = m0 + ty*4 + i;
    if (row < M){
      float4 o = {acc[i][0], acc[i][1], acc[i][2], acc[i][3]};
      *(float4*)(C + (size_t)row*N + n0 + tx*4) = o;
    }
  }
}

// ---------------- layer-1 logits: als/ald [N,4] ----------------
__global__ __launch_bounds__(128) void logits1_kernel(const float* __restrict__ h1,
                                                      const float* __restrict__ a_src,
                                                      const float* __restrict__ a_dst,
                                                      float* __restrict__ als,
                                                      float* __restrict__ ald){
  const int n = blockIdx.x;
  const int tid = threadIdx.x;           // 128 threads, each a float4 of h1[n]
  const int head = tid >> 5;             // 0..3
  const int p = tid & 31;                // float4 index within head
  const float4 v  = ((const float4*)(h1 + (size_t)n*F1))[tid];
  const float4 as = ((const float4*)(a_src + head*HID))[p];
  const float4 ad = ((const float4*)(a_dst + head*HID))[p];
  float ds = v.x*as.x + v.y*as.y + v.z*as.z + v.w*as.w;
  float dd = v.x*ad.x + v.y*ad.y + v.z*ad.z + v.w*ad.w;
  #pragma unroll
  for (int off = 16; off >= 1; off >>= 1){
    ds += __shfl_down(ds, off, 32);
    dd += __shfl_down(dd, off, 32);
  }
  if (p == 0){ als[n*4 + head] = ds; ald[n*4 + head] = dd; }
}

// ---------------- layer-1 aggregation + bias + ELU ----------------
__global__ __launch_bounds__(256) void agg1_kernel(const float* __restrict__ h1,
                                                   const float* __restrict__ als,
                                                   const float* __restrict__ ald1,
                                                   const float* __restrict__ b1,
                                                   const int* __restrict__ offs,
                                                   const int* __restrict__ ssrc,
                                                   float* __restrict__ hout){
  const int n = blockIdx.x;
  const int tid = threadIdx.x;
  const float4 ald = ((const float4*)ald1)[n];
  const int s0 = offs[n], s1 = offs[n+1];

  // pass 1: softmax denominator per head
  float dsum[4] = {0.f,0.f,0.f,0.f};
  for (int e = s0 + tid; e < s1; e += 256){
    const int src = ssrc[e];
    const float4 as = ((const float4*)als)[src];
    dsum[0] += expf(lrelu(as.x + ald.x));
    dsum[1] += expf(lrelu(as.y + ald.y));
    dsum[2] += expf(lrelu(as.z + ald.z));
    dsum[3] += expf(lrelu(as.w + ald.w));
  }
  #pragma unroll
  for (int off = 32; off >= 1; off >>= 1){
    dsum[0] += __shfl_down(dsum[0], off);
    dsum[1] += __shfl_down(dsum[1], off);
    dsum[2] += __shfl_down(dsum[2], off);
    dsum[3] += __shfl_down(dsum[3], off);
  }
  __shared__ float sred[4][4];
  __shared__ float sdenom[4];
  const int lane = tid & 63, wave = tid >> 6;
  if (lane == 0){
    sred[wave][0]=dsum[0]; sred[wave][1]=dsum[1];
    sred[wave][2]=dsum[2]; sred[wave][3]=dsum[3];
  }
  __syncthreads();
  if (tid < 4)
    sdenom[tid] = sred[0][tid] + sred[1][tid] + sred[2][tid] + sred[3][tid] + 1e-16f;
  __syncthreads();

  // pass 2: weighted aggregation, chunked 64 edges at a time
  const int head = tid >> 6;             // wave w handles head w (features w*128..)
  const float aldh = (head==0)?ald.x:(head==1)?ald.y:(head==2)?ald.z:ald.w;
  __shared__ int   shsrc[64];
  __shared__ float salpha[4][64];
  float accx = 0.f, accy = 0.f;
  for (int ce = s0; ce < s1; ce += 64){
    const int nE = min(64, s1 - ce);
    const int idx = tid & 63;            // edge in chunk; head = wave
    if (idx < nE){
      const int sc = ssrc[ce + idx];
      if (head == 0) shsrc[idx] = sc;
      const float a = als[sc*4 + head] + aldh;
      salpha[head][idx] = expf(lrelu(a)) / sdenom[head];
    }
    __syncthreads();
    for (int k = 0; k < nE; ++k){
      const int sc = shsrc[k];
      const float al = salpha[head][k];
      const float2 hv = ((const float2*)(h1 + (size_t)sc*F1))[tid];
      accx = fmaf(hv.x, al, accx);
      accy = fmaf(hv.y, al, accy);
    }
    __syncthreads();
  }
  const float2 bb = ((const float2*)b1)[tid];
  float2 o;
  o.x = elu(accx + bb.x);
  o.y = elu(accy + bb.y);
  ((float2*)(hout + (size_t)n*F1))[tid] = o;
}

// ---------------- layer-2 logits ----------------
__global__ __launch_bounds__(64) void logits2_kernel(const float* __restrict__ g,
                                                     const float* __restrict__ a_src,
                                                     const float* __restrict__ a_dst,
                                                     float* __restrict__ als,
                                                     float* __restrict__ ald){
  const int n = blockIdx.x;
  const int tid = threadIdx.x;
  const float v = g[(size_t)n*F_OUT + tid];
  float ds = v * a_src[tid];
  float dd = v * a_dst[tid];
  #pragma unroll
  for (int off = 32; off >= 1; off >>= 1){
    ds += __shfl_xor(ds, off);
    dd += __shfl_xor(dd, off);
  }
  if (tid == 0){ als[n] = ds; ald[n] = dd; }
}

// ---------------- layer-2 aggregation + bias ----------------
__global__ __launch_bounds__(64) void agg2_kernel(const float* __restrict__ g,
                                                  const float* __restrict__ als,
                                                  const float* __restrict__ ald2,
                                                  const float* __restrict__ b2,
                                                  const int* __restrict__ offs,
                                                  const int* __restrict__ ssrc,
                                                  float* __restrict__ out){
  const int n = blockIdx.x;
  const int tid = threadIdx.x;
  const float ald = ald2[n];
  const int s0 = offs[n], s1 = offs[n+1];

  float dsum = 0.f;
  for (int e = s0 + tid; e < s1; e += 64){
    const float a = als[ssrc[e]] + ald;
    dsum += expf(lrelu(a));
  }
  #pragma unroll
  for (int off = 32; off >= 1; off >>= 1)
    dsum += __shfl_xor(dsum, off);
  const float denom = dsum + 1e-16f;

  __shared__ int   shsrc[64];
  __shared__ float salpha[64];
  float acc = 0.f;
  for (int ce = s0; ce < s1; ce += 64){
    const int nE = min(64, s1 - ce);
    if (tid < nE){
      const int sc = ssrc[ce + tid];
      shsrc[tid] = sc;
      salpha[tid] = expf(lrelu(als[sc] + ald)) / denom;
    }
    __syncthreads();
    for (int k = 0; k < nE; ++k)
      acc = fmaf(g[(size_t)shsrc[k]*F_OUT + tid], salpha[k], acc);
    __syncthreads();
  }
  out[(size_t)n*F_OUT + tid] = acc + b2[tid];
}

extern "C" void kernel_launch(void* const* d_in, const int* in_sizes, int n_in,
                              void* d_out, int out_size, void* d_ws, size_t ws_size,
                              hipStream_t stream){
  const float* x      = (const float*)d_in[0];
  const int*   ei     = (const int*)  d_in[1];
  const float* W1     = (const float*)d_in[2];
  const float* a_src1 = (const float*)d_in[3];
  const float* a_dst1 = (const float*)d_in[4];
  const float* b1     = (const float*)d_in[5];
  const float* W2     = (const float*)d_in[6];
  const float* a_src2 = (const float*)d_in[7];
  const float* a_dst2 = (const float*)d_in[8];
  const float* b2     = (const float*)d_in[9];
  float* out = (float*)d_out;

  char* ws = (char*)d_ws;
  float* h1   = (float*)(ws + 0UL);            // [N,512] = 102.4 MB
  float* hbuf = (float*)(ws + 102400000UL);    // [N,512] = 102.4 MB
  float* als1 = (float*)(ws + 204800000UL);    // [N,4]
  float* ald1 = (float*)(ws + 205600000UL);    // [N,4]
  float* als2 = (float*)(ws + 206400000UL);    // [N]
  float* ald2 = (float*)(ws + 206600000UL);    // [N]
  int*   deg  = (int*)  (ws + 206800000UL);    // [N]
  int*   cur  = (int*)  (ws + 207000000UL);    // [N]
  int*   offs = (int*)  (ws + 207200000UL);    // [N+1]
  int*   ssrc = (int*)  (ws + 207400704UL);    // [E_TOT]
  float* g = h1;                               // reuse h1 for layer-2 features [N,64]

  // zero deg + cur (contiguous 400000 bytes)
  hipMemsetAsync(ws + 206800000UL, 0, 400000, stream);

  const int eb = (E_TOT + 255) / 256;
  hist_kernel   <<<eb, 256, 0, stream>>>(ei, deg);
  scan_kernel   <<<1, 1024, 0, stream>>>(deg, offs);
  scatter_kernel<<<eb, 256, 0, stream>>>(ei, offs, cur, ssrc);

  gemm64<F_IN><<<dim3(782, 8), 256, 0, stream>>>(x, W1, h1, N_NODES, F1);
  logits1_kernel<<<N_NODES, 128, 0, stream>>>(h1, a_src1, a_dst1, als1, ald1);
  agg1_kernel   <<<N_NODES, 256, 0, stream>>>(h1, als1, ald1, b1, offs, ssrc, hbuf);

  gemm64<F1><<<dim3(782, 1), 256, 0, stream>>>(hbuf, W2, g, N_NODES, F_OUT);
  logits2_kernel<<<N_NODES, 64, 0, stream>>>(g, a_src2, a_dst2, als2, ald2);
  agg2_kernel   <<<N_NODES, 64, 0, stream>>>(g, als2, ald2, b2, offs, ssrc, out);
}

// Round 2
// 469.160 us; speedup vs baseline: 1.7299x; 1.7299x over previous
//
#include <hip/hip_runtime.h>
#include <math.h>

#define N_NODES 50000
#define N_EDGES 800000
#define E_TOT   850000
#define F_IN    256
#define F1      512
#define HID     128
#define HEADS   4
#define F_OUT   64

typedef __attribute__((ext_vector_type(8))) short short8;
typedef __attribute__((ext_vector_type(4))) float f32x4;
typedef unsigned short ushort_t;
typedef unsigned int uint_t;

__device__ __forceinline__ float lrelu(float x){ return x > 0.f ? x : 0.2f*x; }
__device__ __forceinline__ float elu(float x){ return x > 0.f ? x : expm1f(x); }

__device__ __forceinline__ ushort_t f2b(float f){
  uint_t u = __builtin_bit_cast(uint_t, f);
  u += 0x7fffu + ((u >> 16) & 1u);
  return (ushort_t)(u >> 16);
}
__device__ __forceinline__ float blo(uint_t u){ return __builtin_bit_cast(float, u << 16); }
__device__ __forceinline__ float bhi(uint_t u){ return __builtin_bit_cast(float, u & 0xffff0000u); }
__device__ __forceinline__ float b2f(ushort_t s){ return __builtin_bit_cast(float, (uint_t)s << 16); }

// ---------------- CSR build ----------------
__global__ void hist_kernel(const int* __restrict__ ei, int* __restrict__ deg){
  int e = blockIdx.x*blockDim.x + threadIdx.x;
  if (e >= E_TOT) return;
  int dst = (e < N_EDGES) ? ei[N_EDGES + e] : (e - N_EDGES);
  atomicAdd(&deg[dst], 1);
}

__global__ __launch_bounds__(256) void scan1_kernel(const int* __restrict__ deg,
                                                    int* __restrict__ offs,
                                                    int* __restrict__ bsum){
  __shared__ int sd[256];
  const int tid = threadIdx.x;
  const int i = blockIdx.x*256 + tid;
  int v = (i < N_NODES) ? deg[i] : 0;
  sd[tid] = v; __syncthreads();
  #pragma unroll
  for (int off = 1; off < 256; off <<= 1){
    int t = (tid >= off) ? sd[tid - off] : 0;
    __syncthreads();
    sd[tid] += t;
    __syncthreads();
  }
  if (i < N_NODES) offs[i] = sd[tid] - v;   // block-local exclusive
  if (tid == 255) bsum[blockIdx.x] = sd[255];
}

__global__ __launch_bounds__(256) void scan2_kernel(const int* __restrict__ bsum,
                                                    int* __restrict__ bbase, int nb){
  __shared__ int sd[256];
  const int tid = threadIdx.x;
  int v = (tid < nb) ? bsum[tid] : 0;
  sd[tid] = v; __syncthreads();
  #pragma unroll
  for (int off = 1; off < 256; off <<= 1){
    int t = (tid >= off) ? sd[tid - off] : 0;
    __syncthreads();
    sd[tid] += t;
    __syncthreads();
  }
  if (tid < nb) bbase[tid] = sd[tid] - v;
}

__global__ __launch_bounds__(256) void scan3_kernel(int* __restrict__ offs,
                                                    const int* __restrict__ bbase,
                                                    int* __restrict__ cur){
  const int i = blockIdx.x*256 + threadIdx.x;
  if (i < N_NODES){
    int o = offs[i] + bbase[blockIdx.x];
    offs[i] = o;
    cur[i] = o;
  }
  if (blockIdx.x == 0 && threadIdx.x == 0) offs[N_NODES] = E_TOT;
}

__global__ void scatter_kernel(const int* __restrict__ ei, int* __restrict__ cur,
                               int* __restrict__ ssrc){
  int e = blockIdx.x*blockDim.x + threadIdx.x;
  if (e >= E_TOT) return;
  int src, dst;
  if (e < N_EDGES){ src = ei[e]; dst = ei[N_EDGES + e]; }
  else            { src = e - N_EDGES; dst = src; }
  int pos = atomicAdd(&cur[dst], 1);
  ssrc[pos] = src;
}

// ---------------- prep: fp32 -> bf16 ----------------
__global__ __launch_bounds__(256) void cvt_x_kernel(const float* __restrict__ x,
                                                    ushort_t* __restrict__ xb){
  const int t = blockIdx.x*256 + threadIdx.x;     // 8 elems/thread
  const float4 a = ((const float4*)x)[t*2];
  const float4 b = ((const float4*)x)[t*2 + 1];
  uint4 o;
  o.x = (uint_t)f2b(a.x) | ((uint_t)f2b(a.y) << 16);
  o.y = (uint_t)f2b(a.z) | ((uint_t)f2b(a.w) << 16);
  o.z = (uint_t)f2b(b.x) | ((uint_t)f2b(b.y) << 16);
  o.w = (uint_t)f2b(b.z) | ((uint_t)f2b(b.w) << 16);
  ((uint4*)xb)[t] = o;
}

// W [K][N] fp32 -> Wt [N][K] bf16   (K,N multiples of 64)
__global__ __launch_bounds__(256) void transpose_bf16_kernel(const float* __restrict__ W,
                                                             ushort_t* __restrict__ Wt,
                                                             int K, int N){
  __shared__ float tile[64][65];
  const int k0 = blockIdx.x*64, n0 = blockIdx.y*64;
  const int c = threadIdx.x & 63, r4 = threadIdx.x >> 6;
  for (int r = r4; r < 64; r += 4)
    tile[r][c] = W[(size_t)(k0 + r)*N + n0 + c];
  __syncthreads();
  for (int r = r4; r < 64; r += 4)
    Wt[(size_t)(n0 + r)*K + k0 + c] = f2b(tile[c][r]);
}

// ---------------- bf16 MFMA GEMM: C[M,N] = A[M,K] @ Bt[N,K]^T ----------------
template<int K, int WR, int WC>
__global__ __launch_bounds__(256) void gemm_bf16(const ushort_t* __restrict__ A,
                                                 const ushort_t* __restrict__ Bt,
                                                 ushort_t* __restrict__ C,
                                                 int M, int N){
  constexpr int BM = WR*64, BN = WC*64, BKP = 40;  // pad 32->40 (80B rows, 16B aligned)
  __shared__ ushort_t As[BM*BKP];
  __shared__ ushort_t Bs[BN*BKP];
  const int tid = threadIdx.x;
  const int wave = tid >> 6, lane = tid & 63, quad = lane >> 4, l16 = lane & 15;
  const int wm = wave % WR, wn = wave / WR;
  const int m0 = blockIdx.x*BM, n0 = blockIdx.y*BN;
  f32x4 acc[4][4] = {};
  for (int k0 = 0; k0 < K; k0 += 32){
    #pragma unroll
    for (int s = tid; s < BM*4; s += 256){
      int r = s >> 2, c = s & 3;
      int gr = m0 + r; if (gr >= M) gr = M - 1;
      *(uint4*)(As + r*BKP + c*8) = *(const uint4*)(A + (size_t)gr*K + k0 + c*8);
    }
    #pragma unroll
    for (int s = tid; s < BN*4; s += 256){
      int r = s >> 2, c = s & 3;
      *(uint4*)(Bs + r*BKP + c*8) = *(const uint4*)(Bt + (size_t)(n0 + r)*K + k0 + c*8);
    }
    __syncthreads();
    short8 af[4], bfr[4];
    #pragma unroll
    for (int i = 0; i < 4; ++i)
      af[i] = *(const short8*)(As + (wm*64 + i*16 + l16)*BKP + quad*8);
    #pragma unroll
    for (int j = 0; j < 4; ++j)
      bfr[j] = *(const short8*)(Bs + (wn*64 + j*16 + l16)*BKP + quad*8);
    #pragma unroll
    for (int i = 0; i < 4; ++i)
      #pragma unroll
      for (int j = 0; j < 4; ++j)
        acc[i][j] = __builtin_amdgcn_mfma_f32_16x16x32_bf16(af[i], bfr[j], acc[i][j], 0, 0, 0);
    __syncthreads();
  }
  #pragma unroll
  for (int i = 0; i < 4; ++i){
    #pragma unroll
    for (int r = 0; r < 4; ++r){
      int row = m0 + wm*64 + i*16 + quad*4 + r;
      if (row < M){
        #pragma unroll
        for (int j = 0; j < 4; ++j){
          int col = n0 + wn*64 + j*16 + l16;
          C[(size_t)row*N + col] = f2b(acc[i][j][r]);
        }
      }
    }
  }
}

// ---------------- layer-1 logits from bf16 h1 ----------------
__global__ __launch_bounds__(128) void logits1_kernel(const ushort_t* __restrict__ h1b,
                                                      const float* __restrict__ a_src,
                                                      const float* __restrict__ a_dst,
                                                      float* __restrict__ als,
                                                      float* __restrict__ ald){
  const int n = blockIdx.x;
  const int tid = threadIdx.x;
  const int head = tid >> 5, p = tid & 31;
  const uint2 v = *(const uint2*)(h1b + (size_t)n*F1 + tid*4);
  float h0 = blo(v.x), h1 = bhi(v.x), h2 = blo(v.y), h3 = bhi(v.y);
  const float4 as = *(const float4*)(a_src + head*HID + p*4);
  const float4 ad = *(const float4*)(a_dst + head*HID + p*4);
  float ds = h0*as.x + h1*as.y + h2*as.z + h3*as.w;
  float dd = h0*ad.x + h1*ad.y + h2*ad.z + h3*ad.w;
  #pragma unroll
  for (int off = 16; off >= 1; off >>= 1){
    ds += __shfl_down(ds, off, 32);
    dd += __shfl_down(dd, off, 32);
  }
  if (p == 0){ als[n*4 + head] = ds; ald[n*4 + head] = dd; }
}

// ---------------- layer-1 aggregation (wave per dst) ----------------
__global__ __launch_bounds__(256) void agg1_kernel(const ushort_t* __restrict__ h1b,
                                                   const float* __restrict__ als,
                                                   const float* __restrict__ ald1,
                                                   const float* __restrict__ b1,
                                                   const int* __restrict__ offs,
                                                   const int* __restrict__ ssrc,
                                                   ushort_t* __restrict__ hb){
  __shared__ int   shsrc[4][64];
  __shared__ float shal[4][64][4];
  const int wave = threadIdx.x >> 6, lane = threadIdx.x & 63;
  const int n = blockIdx.x*4 + wave;
  const int head = lane >> 4;
  const float4 ald = ((const float4*)ald1)[n];
  const int s0 = offs[n], s1 = offs[n+1];

  // pass 1: softmax denominators (all 4 heads)
  float d0 = 0.f, d1 = 0.f, d2 = 0.f, d3 = 0.f;
  for (int e = s0 + lane; e < s1; e += 64){
    const int sc = ssrc[e];
    const float4 as = ((const float4*)als)[sc];
    d0 += __expf(lrelu(as.x + ald.x));
    d1 += __expf(lrelu(as.y + ald.y));
    d2 += __expf(lrelu(as.z + ald.z));
    d3 += __expf(lrelu(as.w + ald.w));
  }
  #pragma unroll
  for (int off = 32; off >= 1; off >>= 1){
    d0 += __shfl_xor(d0, off);
    d1 += __shfl_xor(d1, off);
    d2 += __shfl_xor(d2, off);
    d3 += __shfl_xor(d3, off);
  }
  const float den = (head == 0) ? d0 : (head == 1) ? d1 : (head == 2) ? d2 : d3;
  const float rd = 1.0f / (den + 1e-16f);

  // pass 2: weighted aggregation; lane covers feats lane*8 .. lane*8+7 (head = lane>>4)
  float acc[8] = {0.f,0.f,0.f,0.f,0.f,0.f,0.f,0.f};
  for (int ce = s0; ce < s1; ce += 64){
    const int idx = ce + lane;
    if (idx < s1){
      const int sc = ssrc[idx];
      const float4 as = ((const float4*)als)[sc];
      shsrc[wave][lane] = sc;
      float4 a4;
      a4.x = __expf(lrelu(as.x + ald.x));
      a4.y = __expf(lrelu(as.y + ald.y));
      a4.z = __expf(lrelu(as.z + ald.z));
      a4.w = __expf(lrelu(as.w + ald.w));
      *(float4*)&shal[wave][lane][0] = a4;
    }
    const int nE = min(64, s1 - ce);
    for (int k = 0; k < nE; ++k){
      const int scb = shsrc[wave][k];
      const float al = shal[wave][k][head] * rd;
      const uint4 hv = *(const uint4*)(h1b + (size_t)scb*F1 + lane*8);
      acc[0] = fmaf(blo(hv.x), al, acc[0]);
      acc[1] = fmaf(bhi(hv.x), al, acc[1]);
      acc[2] = fmaf(blo(hv.y), al, acc[2]);
      acc[3] = fmaf(bhi(hv.y), al, acc[3]);
      acc[4] = fmaf(blo(hv.z), al, acc[4]);
      acc[5] = fmaf(bhi(hv.z), al, acc[5]);
      acc[6] = fmaf(blo(hv.w), al, acc[6]);
      acc[7] = fmaf(bhi(hv.w), al, acc[7]);
    }
  }
  const float4 ba = *(const float4*)(b1 + lane*8);
  const float4 bb = *(const float4*)(b1 + lane*8 + 4);
  float o0 = elu(acc[0] + ba.x), o1 = elu(acc[1] + ba.y);
  float o2 = elu(acc[2] + ba.z), o3 = elu(acc[3] + ba.w);
  float o4 = elu(acc[4] + bb.x), o5 = elu(acc[5] + bb.y);
  float o6 = elu(acc[6] + bb.z), o7 = elu(acc[7] + bb.w);
  uint4 o;
  o.x = (uint_t)f2b(o0) | ((uint_t)f2b(o1) << 16);
  o.y = (uint_t)f2b(o2) | ((uint_t)f2b(o3) << 16);
  o.z = (uint_t)f2b(o4) | ((uint_t)f2b(o5) << 16);
  o.w = (uint_t)f2b(o6) | ((uint_t)f2b(o7) << 16);
  *(uint4*)(hb + (size_t)n*F1 + lane*8) = o;
}

// ---------------- layer-2 logits from bf16 g ----------------
__global__ __launch_bounds__(64) void logits2_kernel(const ushort_t* __restrict__ gb,
                                                     const float* __restrict__ a_src,
                                                     const float* __restrict__ a_dst,
                                                     float* __restrict__ als,
                                                     float* __restrict__ ald){
  const int n = blockIdx.x;
  const int tid = threadIdx.x;
  const float v = b2f(gb[(size_t)n*F_OUT + tid]);
  float ds = v * a_src[tid];
  float dd = v * a_dst[tid];
  #pragma unroll
  for (int off = 32; off >= 1; off >>= 1){
    ds += __shfl_xor(ds, off);
    dd += __shfl_xor(dd, off);
  }
  if (tid == 0){ als[n] = ds; ald[n] = dd; }
}

// ---------------- layer-2 aggregation (wave per dst) ----------------
__global__ __launch_bounds__(256) void agg2_kernel(const ushort_t* __restrict__ gb,
                                                   const float* __restrict__ als,
                                                   const float* __restrict__ ald2,
                                                   const float* __restrict__ b2,
                                                   const int* __restrict__ offs,
                                                   const int* __restrict__ ssrc,
                                                   float* __restrict__ out){
  __shared__ int   shsrc[4][64];
  __shared__ float shal[4][64];
  const int wave = threadIdx.x >> 6, lane = threadIdx.x & 63;
  const int n = blockIdx.x*4 + wave;
  const float ald = ald2[n];
  const int s0 = offs[n], s1 = offs[n+1];

  float dsum = 0.f;
  for (int e = s0 + lane; e < s1; e += 64)
    dsum += __expf(lrelu(als[ssrc[e]] + ald));
  #pragma unroll
  for (int off = 32; off >= 1; off >>= 1)
    dsum += __shfl_xor(dsum, off);
  const float rd = 1.0f / (dsum + 1e-16f);

  float acc = 0.f;
  for (int ce = s0; ce < s1; ce += 64){
    const int idx = ce + lane;
    if (idx < s1){
      const int sc = ssrc[idx];
      shsrc[wave][lane] = sc;
      shal[wave][lane] = __expf(lrelu(als[sc] + ald)) * rd;
    }
    const int nE = min(64, s1 - ce);
    for (int k = 0; k < nE; ++k){
      const int scb = shsrc[wave][k];
      const float al = shal[wave][k];
      acc = fmaf(b2f(gb[(size_t)scb*F_OUT + lane]), al, acc);
    }
  }
  out[(size_t)n*F_OUT + lane] = acc + b2[lane];
}

extern "C" void kernel_launch(void* const* d_in, const int* in_sizes, int n_in,
                              void* d_out, int out_size, void* d_ws, size_t ws_size,
                              hipStream_t stream){
  const float* x      = (const float*)d_in[0];
  const int*   ei     = (const int*)  d_in[1];
  const float* W1     = (const float*)d_in[2];
  const float* a_src1 = (const float*)d_in[3];
  const float* a_dst1 = (const float*)d_in[4];
  const float* b1     = (const float*)d_in[5];
  const float* W2     = (const float*)d_in[6];
  const float* a_src2 = (const float*)d_in[7];
  const float* a_dst2 = (const float*)d_in[8];
  const float* b2     = (const float*)d_in[9];
  float* out = (float*)d_out;

  char* ws = (char*)d_ws;
  ushort_t* h1b  = (ushort_t*)(ws + 0UL);            // [N,512] bf16 = 51.2 MB
  ushort_t* hb   = (ushort_t*)(ws + 51200000UL);     // [N,512] bf16 = 51.2 MB
  ushort_t* xb   = (ushort_t*)(ws + 102400000UL);    // [N,256] bf16 = 25.6 MB
  ushort_t* gb   = (ushort_t*)(ws + 128000000UL);    // [N,64]  bf16 = 6.4 MB
  ushort_t* W1t  = (ushort_t*)(ws + 134400000UL);    // [512][256] bf16
  ushort_t* W2t  = (ushort_t*)(ws + 134662144UL);    // [64][512] bf16
  float*    als1 = (float*)   (ws + 134727680UL);    // [N,4]
  float*    ald1 = (float*)   (ws + 135527680UL);    // [N,4]
  float*    als2 = (float*)   (ws + 136327680UL);    // [N]
  float*    ald2 = (float*)   (ws + 136527680UL);    // [N]
  int*      deg  = (int*)     (ws + 136727680UL);    // [N]
  int*      offs = (int*)     (ws + 136927680UL);    // [N+1]
  int*      bsum = (int*)     (ws + 137127744UL);    // [196]
  int*      bbase= (int*)     (ws + 137128544UL);    // [196]
  int*      cur  = (int*)     (ws + 137129600UL);    // [N]
  int*      ssrc = (int*)     (ws + 137329600UL);    // [E_TOT] = 3.4 MB

  hipMemsetAsync(deg, 0, 200000, stream);

  const int eb = (E_TOT + 255) / 256;
  const int nb = (N_NODES + 255) / 256;              // 196
  hist_kernel   <<<eb, 256, 0, stream>>>(ei, deg);
  scan1_kernel  <<<nb, 256, 0, stream>>>(deg, offs, bsum);
  scan2_kernel  <<<1, 256, 0, stream>>>(bsum, bbase, nb);
  scan3_kernel  <<<nb, 256, 0, stream>>>(offs, bbase, cur);
  scatter_kernel<<<eb, 256, 0, stream>>>(ei, cur, ssrc);

  cvt_x_kernel        <<<6250, 256, 0, stream>>>(x, xb);
  transpose_bf16_kernel<<<dim3(4, 8), 256, 0, stream>>>(W1, W1t, F_IN, F1);
  transpose_bf16_kernel<<<dim3(8, 1), 256, 0, stream>>>(W2, W2t, F1, F_OUT);

  gemm_bf16<F_IN, 2, 2><<<dim3(391, 4), 256, 0, stream>>>(xb, W1t, h1b, N_NODES, F1);
  logits1_kernel<<<N_NODES, 128, 0, stream>>>(h1b, a_src1, a_dst1, als1, ald1);
  agg1_kernel   <<<12500, 256, 0, stream>>>(h1b, als1, ald1, b1, offs, ssrc, hb);

  gemm_bf16<F1, 4, 1><<<dim3(196, 1), 256, 0, stream>>>(hb, W2t, gb, N_NODES, F_OUT);
  logits2_kernel<<<N_NODES, 64, 0, stream>>>(gb, a_src2, a_dst2, als2, ald2);
  agg2_kernel   <<<12500, 256, 0, stream>>>(gb, als2, ald2, b2, offs, ssrc, out);
}